// Round 1
// baseline (5153.626 us; speedup 1.0000x reference)
//
#include <hip/hip_runtime.h>
#include <math.h>

#define GRID_SZ 128
#define NC 196
#define NC4 49            // NC/4 float4 per row
#define G2 (GRID_SZ*GRID_SZ)  // 16384

struct Slot {
    int tag;      // cell id, -1 = empty
    float den;    // accumulated alpha (wave-uniform value)
    float4 acc;   // this lane's 4 channels' accumulated alpha*feat
};

__device__ __forceinline__ void slot_flush(const Slot& s, float* __restrict__ out,
                                           float* __restrict__ den,
                                           size_t outPlaneBase, int denPlaneBase,
                                           int lane) {
    if (s.tag < 0) return;
    if (lane < NC4) {
        size_t base = outPlaneBase + (size_t)(4 * lane) * G2 + (size_t)s.tag;
        unsafeAtomicAdd(out + base,                 s.acc.x);
        unsafeAtomicAdd(out + base + (size_t)G2,    s.acc.y);
        unsafeAtomicAdd(out + base + (size_t)2*G2,  s.acc.z);
        unsafeAtomicAdd(out + base + (size_t)3*G2,  s.acc.w);
    }
    if (lane == 0) {
        unsafeAtomicAdd(den + denPlaneBase + s.tag, s.den);
    }
}

__device__ __forceinline__ void plane_acc(Slot& a, Slot& b, int cell, float alpha,
                                          const float4& av,
                                          float* __restrict__ out, float* __restrict__ den,
                                          size_t outPlaneBase, int denPlaneBase, int lane) {
    if (cell == a.tag) {
        a.acc.x += av.x; a.acc.y += av.y; a.acc.z += av.z; a.acc.w += av.w;
        a.den += alpha;
    } else if (cell == b.tag) {
        b.acc.x += av.x; b.acc.y += av.y; b.acc.z += av.z; b.acc.w += av.w;
        b.den += alpha;
    } else {
        // keep the heavier accumulator resident in slot A (sticky-hot)
        if (b.den > a.den) { Slot t = a; a = b; b = t; }
        slot_flush(b, out, den, outPlaneBase, denPlaneBase, lane);
        b.tag = cell; b.den = alpha; b.acc = av;
    }
}

__global__ __launch_bounds__(256) void splat_kernel(
    const float* __restrict__ gs, const float* __restrict__ sb,
    float* __restrict__ out, float* __restrict__ den,
    int B, int N, int ppw) {
    const int lane = threadIdx.x & 63;
    const long long wave = (long long)blockIdx.x * (blockDim.x >> 6) + (threadIdx.x >> 6);
    const long long totalPts = (long long)B * N;
    long long start = wave * ppw;
    if (start >= totalPts) return;
    long long end = start + ppw;                // ppw divides N, never crosses batch
    if (end > totalPts) end = totalPts;
    const int bb = (int)(start / N);

    const float lo0 = sb[0], hi0 = sb[1];
    const float lo1 = sb[2], hi1 = sb[3];
    const float lo2 = sb[4], hi2 = sb[5];
    const float s0 = 2.0f / (hi0 - lo0);
    const float s1 = 2.0f / (hi1 - lo1);
    const float s2 = 2.0f / (hi2 - lo2);

    const size_t ob0 = ((size_t)(bb * 3 + 0) * NC) * G2;
    const size_t ob1 = ((size_t)(bb * 3 + 1) * NC) * G2;
    const size_t ob2 = ((size_t)(bb * 3 + 2) * NC) * G2;
    const int db0 = (bb * 3 + 0) * G2;
    const int db1 = (bb * 3 + 1) * G2;
    const int db2 = (bb * 3 + 2) * G2;

    const float4 f40 = make_float4(0.f, 0.f, 0.f, 0.f);
    Slot a0{-1, 0.f, f40}, t0{-1, 0.f, f40};
    Slot a1{-1, 0.f, f40}, t1{-1, 0.f, f40};
    Slot a2{-1, 0.f, f40}, t2{-1, 0.f, f40};

    const float4* rows = (const float4*)gs;

    // prefetch first point
    const float4* r0 = rows + (size_t)start * NC4;
    float4 v = (lane < NC4) ? r0[lane] : f40;
    float4 h = r0[0];

    for (long long i = start; i < end; ++i) {
        float4 vn = f40, hn = f40;
        if (i + 1 < end) {
            const float4* rn = rows + (size_t)(i + 1) * NC4;
            vn = (lane < NC4) ? rn[lane] : f40;
            hn = rn[0];
        }

        // head = (x, y, z, f3), identical in every lane
        const float cnx = (h.x - lo0) * s0 - 1.0f;
        const float cny = (h.y - lo1) * s1 - 1.0f;
        const float cnz = (h.z - lo2) * s2 - 1.0f;
        int gx = (int)((cnx * 0.5f + 0.5f) * 127.0f);
        int gy = (int)((cny * 0.5f + 0.5f) * 127.0f);
        int gz = (int)((cnz * 0.5f + 0.5f) * 127.0f);
        gx = min(127, max(0, gx));
        gy = min(127, max(0, gy));
        gz = min(127, max(0, gz));
        const int cxy = __builtin_amdgcn_readfirstlane(gx * GRID_SZ + gy);
        const int cxz = __builtin_amdgcn_readfirstlane(gx * GRID_SZ + gz);
        const int cyz = __builtin_amdgcn_readfirstlane(gy * GRID_SZ + gz);

        const float alpha = 1.0f / (1.0f + __expf(-h.w));

        float4 vv = v;
        if (lane == 0) { vv.x = cnx; vv.y = cny; vv.z = cnz; }  // feats[:3] = coords_n
        const float4 av = make_float4(vv.x * alpha, vv.y * alpha, vv.z * alpha, vv.w * alpha);

        plane_acc(a0, t0, cxy, alpha, av, out, den, ob0, db0, lane);
        plane_acc(a1, t1, cxz, alpha, av, out, den, ob1, db1, lane);
        plane_acc(a2, t2, cyz, alpha, av, out, den, ob2, db2, lane);

        v = vn; h = hn;
    }

    slot_flush(a0, out, den, ob0, db0, lane);
    slot_flush(t0, out, den, ob0, db0, lane);
    slot_flush(a1, out, den, ob1, db1, lane);
    slot_flush(t1, out, den, ob1, db1, lane);
    slot_flush(a2, out, den, ob2, db2, lane);
    slot_flush(t2, out, den, ob2, db2, lane);
}

__global__ void zero_kernel(float4* __restrict__ p, long long n4) {
    long long i = (long long)blockIdx.x * blockDim.x + threadIdx.x;
    long long stride = (long long)gridDim.x * blockDim.x;
    const float4 z = make_float4(0.f, 0.f, 0.f, 0.f);
    for (; i < n4; i += stride) p[i] = z;
}

__global__ void normalize_kernel(float* __restrict__ out, const float* __restrict__ den,
                                 int total4) {
    int idx = blockIdx.x * blockDim.x + threadIdx.x;
    const int stride = gridDim.x * blockDim.x;
    for (; idx < total4; idx += stride) {
        float4 v = ((float4*)out)[idx];
        const int e = idx * 4;
        const int cell = e & (G2 - 1);
        const int bp = e / (NC * G2);
        const float4 d = *(const float4*)(den + bp * G2 + cell);
        v.x /= fmaxf(d.x, 1e-6f);
        v.y /= fmaxf(d.y, 1e-6f);
        v.z /= fmaxf(d.z, 1e-6f);
        v.w /= fmaxf(d.w, 1e-6f);
        ((float4*)out)[idx] = v;
    }
}

extern "C" void kernel_launch(void* const* d_in, const int* in_sizes, int n_in,
                              void* d_out, int out_size, void* d_ws, size_t ws_size,
                              hipStream_t stream) {
    const float* gs = (const float*)d_in[0];
    const float* sb = (const float*)d_in[1];
    float* out = (float*)d_out;
    float* den = (float*)d_ws;

    const int B = out_size / (3 * NC * G2);                       // 4
    const long long N = (long long)in_sizes[0] / ((long long)B * NC);  // 131072

    const long long out4 = (long long)out_size / 4;
    const long long den4 = ((long long)B * 3 * G2) / 4;

    zero_kernel<<<2048, 256, 0, stream>>>((float4*)out, out4);
    zero_kernel<<<256, 256, 0, stream>>>((float4*)den, den4);

    const int PPW = 64;  // points per wave; divides N
    const long long waves = ((long long)B * N) / PPW;
    const int blocks = (int)((waves + 3) / 4);  // 4 waves per 256-thread block
    splat_kernel<<<blocks, 256, 0, stream>>>(gs, sb, out, den, B, (int)N, PPW);

    normalize_kernel<<<4096, 256, 0, stream>>>(out, den, (int)out4);
}

// Round 2
// 3958.523 us; speedup vs baseline: 1.3019x; 1.3019x over previous
//
#include <hip/hip_runtime.h>
#include <math.h>

#define GRID_SZ 128
#define NC 196
#define NC4 49                // NC/4 float4 per row
#define G2 (GRID_SZ*GRID_SZ)  // 16384

struct Slot {
    int tag;      // cell id, -1 = empty
    float den;    // accumulated alpha (wave-uniform value)
    float4 acc;   // this lane's 4 channels' accumulated alpha*feat
};

// ---------- cell-major (workspace) path ----------

__device__ __forceinline__ void slot_flush_cm(const Slot& s, float* __restrict__ nw,
                                              float* __restrict__ dn,
                                              size_t nwPlaneBase, int dnPlaneBase,
                                              int lane) {
    if (s.tag < 0) return;
    if (lane < NC4) {
        float* base = nw + nwPlaneBase + (size_t)s.tag * NC + 4 * lane;
        unsafeAtomicAdd(base + 0, s.acc.x);
        unsafeAtomicAdd(base + 1, s.acc.y);
        unsafeAtomicAdd(base + 2, s.acc.z);
        unsafeAtomicAdd(base + 3, s.acc.w);
    } else if (lane == NC4) {
        unsafeAtomicAdd(dn + dnPlaneBase + s.tag, s.den);
    }
}

__device__ __forceinline__ void plane_acc_cm(Slot& a, Slot& b, int cell, float alpha,
                                             const float4& av,
                                             float* __restrict__ nw, float* __restrict__ dn,
                                             size_t nwPlaneBase, int dnPlaneBase, int lane) {
    if (cell == a.tag) {
        a.acc.x += av.x; a.acc.y += av.y; a.acc.z += av.z; a.acc.w += av.w;
        a.den += alpha;
    } else if (cell == b.tag) {
        b.acc.x += av.x; b.acc.y += av.y; b.acc.z += av.z; b.acc.w += av.w;
        b.den += alpha;
    } else {
        if (b.den > a.den) { Slot t = a; a = b; b = t; }  // sticky-hot in A
        slot_flush_cm(b, nw, dn, nwPlaneBase, dnPlaneBase, lane);
        b.tag = cell; b.den = alpha; b.acc = av;
    }
}

__global__ __launch_bounds__(256) void splat_cm_kernel(
    const float* __restrict__ gs, const float* __restrict__ sb,
    float* __restrict__ nw, float* __restrict__ dn,
    int B, int N, int ppw) {
    const int lane = threadIdx.x & 63;
    const long long wave = (long long)blockIdx.x * (blockDim.x >> 6) + (threadIdx.x >> 6);
    const long long totalPts = (long long)B * N;
    long long start = wave * ppw;
    if (start >= totalPts) return;
    long long end = start + ppw;
    if (end > totalPts) end = totalPts;
    const int bb = (int)(start / N);

    const float lo0 = sb[0], hi0 = sb[1];
    const float lo1 = sb[2], hi1 = sb[3];
    const float lo2 = sb[4], hi2 = sb[5];
    const float s0 = 2.0f / (hi0 - lo0);
    const float s1 = 2.0f / (hi1 - lo1);
    const float s2 = 2.0f / (hi2 - lo2);

    const size_t pb0 = (size_t)(bb * 3 + 0) * G2 * NC;
    const size_t pb1 = (size_t)(bb * 3 + 1) * G2 * NC;
    const size_t pb2 = (size_t)(bb * 3 + 2) * G2 * NC;
    const int db0 = (bb * 3 + 0) * G2;
    const int db1 = (bb * 3 + 1) * G2;
    const int db2 = (bb * 3 + 2) * G2;

    const float4 f40 = make_float4(0.f, 0.f, 0.f, 0.f);
    Slot a0{-1, 0.f, f40}, t0{-1, 0.f, f40};
    Slot a1{-1, 0.f, f40}, t1{-1, 0.f, f40};
    Slot a2{-1, 0.f, f40}, t2{-1, 0.f, f40};

    const float4* rows = (const float4*)gs;

    const float4* r0 = rows + (size_t)start * NC4;
    float4 v = (lane < NC4) ? r0[lane] : f40;
    float4 h = r0[0];

    for (long long i = start; i < end; ++i) {
        float4 vn = f40, hn = f40;
        if (i + 1 < end) {
            const float4* rn = rows + (size_t)(i + 1) * NC4;
            vn = (lane < NC4) ? rn[lane] : f40;
            hn = rn[0];
        }

        const float cnx = (h.x - lo0) * s0 - 1.0f;
        const float cny = (h.y - lo1) * s1 - 1.0f;
        const float cnz = (h.z - lo2) * s2 - 1.0f;
        int gx = (int)((cnx * 0.5f + 0.5f) * 127.0f);
        int gy = (int)((cny * 0.5f + 0.5f) * 127.0f);
        int gz = (int)((cnz * 0.5f + 0.5f) * 127.0f);
        gx = min(127, max(0, gx));
        gy = min(127, max(0, gy));
        gz = min(127, max(0, gz));
        const int cxy = __builtin_amdgcn_readfirstlane(gx * GRID_SZ + gy);
        const int cxz = __builtin_amdgcn_readfirstlane(gx * GRID_SZ + gz);
        const int cyz = __builtin_amdgcn_readfirstlane(gy * GRID_SZ + gz);

        const float alpha = 1.0f / (1.0f + __expf(-h.w));

        float4 vv = v;
        if (lane == 0) { vv.x = cnx; vv.y = cny; vv.z = cnz; }
        const float4 av = make_float4(vv.x * alpha, vv.y * alpha, vv.z * alpha, vv.w * alpha);

        plane_acc_cm(a0, t0, cxy, alpha, av, nw, dn, pb0, db0, lane);
        plane_acc_cm(a1, t1, cxz, alpha, av, nw, dn, pb1, db1, lane);
        plane_acc_cm(a2, t2, cyz, alpha, av, nw, dn, pb2, db2, lane);

        v = vn; h = hn;
    }

    slot_flush_cm(a0, nw, dn, pb0, db0, lane);
    slot_flush_cm(t0, nw, dn, pb0, db0, lane);
    slot_flush_cm(a1, nw, dn, pb1, db1, lane);
    slot_flush_cm(t1, nw, dn, pb1, db1, lane);
    slot_flush_cm(a2, nw, dn, pb2, db2, lane);
    slot_flush_cm(t2, nw, dn, pb2, db2, lane);
}

#define TCELLS 64
__global__ __launch_bounds__(256) void xpose_kernel(const float* __restrict__ nw,
                                                    const float* __restrict__ dn,
                                                    float* __restrict__ out) {
    __shared__ float tile[TCELLS][197];   // pad 197: conflict-free column reads
    __shared__ float dinv[TCELLS];
    const int t = threadIdx.x;
    const int pg = blockIdx.x >> 8;              // plane index 0..B*3-1 (256 tiles/plane)
    const int c0 = (blockIdx.x & 255) * TCELLS;  // first cell of tile

    const float* src = nw + ((size_t)pg * G2 + c0) * NC;
    for (int i = t; i < TCELLS * NC4; i += 256) {
        const int cell = i / NC4;
        const int cp = i - cell * NC4;
        float4 v = ((const float4*)(src + (size_t)cell * NC))[cp];
        float* dst = &tile[cell][cp * 4];
        dst[0] = v.x; dst[1] = v.y; dst[2] = v.z; dst[3] = v.w;
    }
    if (t < TCELLS) dinv[t] = 1.0f / fmaxf(dn[pg * G2 + c0 + t], 1e-6f);
    __syncthreads();

    float* obase = out + (size_t)pg * NC * G2 + c0;
    for (int i = t; i < TCELLS * NC; i += 256) {
        const int c = i >> 6;
        const int cell = i & 63;
        obase[(size_t)c * G2 + cell] = tile[cell][c] * dinv[cell];
    }
}

// ---------- fallback (direct-to-out channel-major) path ----------

__device__ __forceinline__ void slot_flush(const Slot& s, float* __restrict__ out,
                                           float* __restrict__ den,
                                           size_t outPlaneBase, int denPlaneBase,
                                           int lane) {
    if (s.tag < 0) return;
    if (lane < NC4) {
        size_t base = outPlaneBase + (size_t)(4 * lane) * G2 + (size_t)s.tag;
        unsafeAtomicAdd(out + base,                 s.acc.x);
        unsafeAtomicAdd(out + base + (size_t)G2,    s.acc.y);
        unsafeAtomicAdd(out + base + (size_t)2*G2,  s.acc.z);
        unsafeAtomicAdd(out + base + (size_t)3*G2,  s.acc.w);
    }
    if (lane == 0) unsafeAtomicAdd(den + denPlaneBase + s.tag, s.den);
}

__device__ __forceinline__ void plane_acc(Slot& a, Slot& b, int cell, float alpha,
                                          const float4& av,
                                          float* __restrict__ out, float* __restrict__ den,
                                          size_t outPlaneBase, int denPlaneBase, int lane) {
    if (cell == a.tag) {
        a.acc.x += av.x; a.acc.y += av.y; a.acc.z += av.z; a.acc.w += av.w;
        a.den += alpha;
    } else if (cell == b.tag) {
        b.acc.x += av.x; b.acc.y += av.y; b.acc.z += av.z; b.acc.w += av.w;
        b.den += alpha;
    } else {
        if (b.den > a.den) { Slot t = a; a = b; b = t; }
        slot_flush(b, out, den, outPlaneBase, denPlaneBase, lane);
        b.tag = cell; b.den = alpha; b.acc = av;
    }
}

__global__ __launch_bounds__(256) void splat_kernel(
    const float* __restrict__ gs, const float* __restrict__ sb,
    float* __restrict__ out, float* __restrict__ den,
    int B, int N, int ppw) {
    const int lane = threadIdx.x & 63;
    const long long wave = (long long)blockIdx.x * (blockDim.x >> 6) + (threadIdx.x >> 6);
    const long long totalPts = (long long)B * N;
    long long start = wave * ppw;
    if (start >= totalPts) return;
    long long end = start + ppw;
    if (end > totalPts) end = totalPts;
    const int bb = (int)(start / N);

    const float lo0 = sb[0], hi0 = sb[1];
    const float lo1 = sb[2], hi1 = sb[3];
    const float lo2 = sb[4], hi2 = sb[5];
    const float s0 = 2.0f / (hi0 - lo0);
    const float s1 = 2.0f / (hi1 - lo1);
    const float s2 = 2.0f / (hi2 - lo2);

    const size_t ob0 = ((size_t)(bb * 3 + 0) * NC) * G2;
    const size_t ob1 = ((size_t)(bb * 3 + 1) * NC) * G2;
    const size_t ob2 = ((size_t)(bb * 3 + 2) * NC) * G2;
    const int db0 = (bb * 3 + 0) * G2;
    const int db1 = (bb * 3 + 1) * G2;
    const int db2 = (bb * 3 + 2) * G2;

    const float4 f40 = make_float4(0.f, 0.f, 0.f, 0.f);
    Slot a0{-1, 0.f, f40}, t0{-1, 0.f, f40};
    Slot a1{-1, 0.f, f40}, t1{-1, 0.f, f40};
    Slot a2{-1, 0.f, f40}, t2{-1, 0.f, f40};

    const float4* rows = (const float4*)gs;
    const float4* r0 = rows + (size_t)start * NC4;
    float4 v = (lane < NC4) ? r0[lane] : f40;
    float4 h = r0[0];

    for (long long i = start; i < end; ++i) {
        float4 vn = f40, hn = f40;
        if (i + 1 < end) {
            const float4* rn = rows + (size_t)(i + 1) * NC4;
            vn = (lane < NC4) ? rn[lane] : f40;
            hn = rn[0];
        }
        const float cnx = (h.x - lo0) * s0 - 1.0f;
        const float cny = (h.y - lo1) * s1 - 1.0f;
        const float cnz = (h.z - lo2) * s2 - 1.0f;
        int gx = (int)((cnx * 0.5f + 0.5f) * 127.0f);
        int gy = (int)((cny * 0.5f + 0.5f) * 127.0f);
        int gz = (int)((cnz * 0.5f + 0.5f) * 127.0f);
        gx = min(127, max(0, gx));
        gy = min(127, max(0, gy));
        gz = min(127, max(0, gz));
        const int cxy = __builtin_amdgcn_readfirstlane(gx * GRID_SZ + gy);
        const int cxz = __builtin_amdgcn_readfirstlane(gx * GRID_SZ + gz);
        const int cyz = __builtin_amdgcn_readfirstlane(gy * GRID_SZ + gz);

        const float alpha = 1.0f / (1.0f + __expf(-h.w));

        float4 vv = v;
        if (lane == 0) { vv.x = cnx; vv.y = cny; vv.z = cnz; }
        const float4 av = make_float4(vv.x * alpha, vv.y * alpha, vv.z * alpha, vv.w * alpha);

        plane_acc(a0, t0, cxy, alpha, av, out, den, ob0, db0, lane);
        plane_acc(a1, t1, cxz, alpha, av, out, den, ob1, db1, lane);
        plane_acc(a2, t2, cyz, alpha, av, out, den, ob2, db2, lane);

        v = vn; h = hn;
    }

    slot_flush(a0, out, den, ob0, db0, lane);
    slot_flush(t0, out, den, ob0, db0, lane);
    slot_flush(a1, out, den, ob1, db1, lane);
    slot_flush(t1, out, den, ob1, db1, lane);
    slot_flush(a2, out, den, ob2, db2, lane);
    slot_flush(t2, out, den, ob2, db2, lane);
}

__global__ void zero_kernel(float4* __restrict__ p, long long n4) {
    long long i = (long long)blockIdx.x * blockDim.x + threadIdx.x;
    long long stride = (long long)gridDim.x * blockDim.x;
    const float4 z = make_float4(0.f, 0.f, 0.f, 0.f);
    for (; i < n4; i += stride) p[i] = z;
}

__global__ void normalize_kernel(float* __restrict__ out, const float* __restrict__ den,
                                 int total4) {
    int idx = blockIdx.x * blockDim.x + threadIdx.x;
    const int stride = gridDim.x * blockDim.x;
    for (; idx < total4; idx += stride) {
        float4 v = ((float4*)out)[idx];
        const int e = idx * 4;
        const int cell = e & (G2 - 1);
        const int bp = e / (NC * G2);
        const float4 d = *(const float4*)(den + bp * G2 + cell);
        v.x /= fmaxf(d.x, 1e-6f);
        v.y /= fmaxf(d.y, 1e-6f);
        v.z /= fmaxf(d.z, 1e-6f);
        v.w /= fmaxf(d.w, 1e-6f);
        ((float4*)out)[idx] = v;
    }
}

extern "C" void kernel_launch(void* const* d_in, const int* in_sizes, int n_in,
                              void* d_out, int out_size, void* d_ws, size_t ws_size,
                              hipStream_t stream) {
    const float* gs = (const float*)d_in[0];
    const float* sb = (const float*)d_in[1];
    float* out = (float*)d_out;

    const int B = out_size / (3 * NC * G2);                            // 4
    const long long N = (long long)in_sizes[0] / ((long long)B * NC);  // 131072

    const int PPW = 64;
    const long long waves = ((long long)B * N) / PPW;
    const int blocks = (int)((waves + 3) / 4);

    const size_t nwFloats = (size_t)B * 3 * G2 * NC;      // 38.5M
    const size_t dnFloats = (size_t)B * 3 * G2;           // 196K
    const size_t needBytes = (nwFloats + dnFloats) * sizeof(float);

    if (ws_size >= needBytes) {
        float* nw = (float*)d_ws;
        float* dn = nw + nwFloats;
        const long long z4 = (long long)(nwFloats + dnFloats) / 4;
        zero_kernel<<<2048, 256, 0, stream>>>((float4*)d_ws, z4);
        splat_cm_kernel<<<blocks, 256, 0, stream>>>(gs, sb, nw, dn, B, (int)N, PPW);
        const int xblocks = B * 3 * (G2 / TCELLS);        // 3072
        xpose_kernel<<<xblocks, 256, 0, stream>>>(nw, dn, out);
    } else {
        float* den = (float*)d_ws;
        const long long out4 = (long long)out_size / 4;
        const long long den4 = (long long)dnFloats / 4;
        zero_kernel<<<2048, 256, 0, stream>>>((float4*)out, out4);
        zero_kernel<<<256, 256, 0, stream>>>((float4*)den, den4);
        splat_kernel<<<blocks, 256, 0, stream>>>(gs, sb, out, den, B, (int)N, PPW);
        normalize_kernel<<<4096, 256, 0, stream>>>(out, den, (int)out4);
    }
}

// Round 3
// 1658.907 us; speedup vs baseline: 3.1066x; 2.3862x over previous
//
#include <hip/hip_runtime.h>
#include <math.h>

#define GRID_SZ 128
#define NC 196
#define NC4 49                // NC/4 float4 per row
#define G2 (GRID_SZ*GRID_SZ)  // 16384

struct Slot {
    int tag;      // cell id, -1 = empty
    float den;    // accumulated alpha (wave-uniform value)
    float4 acc;   // this lane's 4 channels' accumulated alpha*feat
};

// ---------- cell-major (workspace) path ----------

__device__ __forceinline__ void slot_flush_cm(const Slot& s, float* __restrict__ nw,
                                              float* __restrict__ dn,
                                              size_t nwPlaneBase, int dnPlaneBase,
                                              int lane) {
    if (s.tag < 0) return;
    if (lane < NC4) {
        float* base = nw + nwPlaneBase + (size_t)s.tag * NC + 4 * lane;
        unsafeAtomicAdd(base + 0, s.acc.x);
        unsafeAtomicAdd(base + 1, s.acc.y);
        unsafeAtomicAdd(base + 2, s.acc.z);
        unsafeAtomicAdd(base + 3, s.acc.w);
    } else if (lane == NC4) {
        unsafeAtomicAdd(dn + dnPlaneBase + s.tag, s.den);
    }
}

// 3-slot cache, min-den eviction: keeps the (data-dependent) hot cells resident.
__device__ __forceinline__ void plane_acc3(Slot& a, Slot& b, Slot& c,
                                           int cell, float alpha, const float4& av,
                                           float* __restrict__ nw, float* __restrict__ dn,
                                           size_t nwPlaneBase, int dnPlaneBase, int lane) {
    if (cell == a.tag) {
        a.acc.x += av.x; a.acc.y += av.y; a.acc.z += av.z; a.acc.w += av.w;
        a.den += alpha;
    } else if (cell == b.tag) {
        b.acc.x += av.x; b.acc.y += av.y; b.acc.z += av.z; b.acc.w += av.w;
        b.den += alpha;
    } else if (cell == c.tag) {
        c.acc.x += av.x; c.acc.y += av.y; c.acc.z += av.z; c.acc.w += av.w;
        c.den += alpha;
    } else {
        // evict the lightest slot (wave-uniform branch)
        if (c.den <= a.den && c.den <= b.den) {
            slot_flush_cm(c, nw, dn, nwPlaneBase, dnPlaneBase, lane);
            c.tag = cell; c.den = alpha; c.acc = av;
        } else if (b.den <= a.den) {
            slot_flush_cm(b, nw, dn, nwPlaneBase, dnPlaneBase, lane);
            b.tag = cell; b.den = alpha; b.acc = av;
        } else {
            slot_flush_cm(a, nw, dn, nwPlaneBase, dnPlaneBase, lane);
            a.tag = cell; a.den = alpha; a.acc = av;
        }
    }
}

__global__ __launch_bounds__(256) void splat_cm_kernel(
    const float* __restrict__ gs, const float* __restrict__ sb,
    float* __restrict__ nw, float* __restrict__ dn,
    int B, int N, int ppw, int K, size_t copyNw, size_t copyDn) {
    const int lane = threadIdx.x & 63;
    const long long wave = (long long)blockIdx.x * (blockDim.x >> 6) + (threadIdx.x >> 6);
    const long long totalPts = (long long)B * N;
    long long start = wave * ppw;
    if (start >= totalPts) return;
    long long end = start + ppw;
    if (end > totalPts) end = totalPts;
    const int bb = (int)(start / N);

    // replica selection: spread contention across K private copies
    const int rep = (int)(blockIdx.x % (unsigned)K);
    float* nwr = nw + (size_t)rep * copyNw;
    float* dnr = dn + (size_t)rep * copyDn;

    const float lo0 = sb[0], hi0 = sb[1];
    const float lo1 = sb[2], hi1 = sb[3];
    const float lo2 = sb[4], hi2 = sb[5];
    const float s0 = 2.0f / (hi0 - lo0);
    const float s1 = 2.0f / (hi1 - lo1);
    const float s2 = 2.0f / (hi2 - lo2);

    const size_t pb0 = (size_t)(bb * 3 + 0) * G2 * NC;
    const size_t pb1 = (size_t)(bb * 3 + 1) * G2 * NC;
    const size_t pb2 = (size_t)(bb * 3 + 2) * G2 * NC;
    const int db0 = (bb * 3 + 0) * G2;
    const int db1 = (bb * 3 + 1) * G2;
    const int db2 = (bb * 3 + 2) * G2;

    const float4 f40 = make_float4(0.f, 0.f, 0.f, 0.f);
    Slot a0{-1, 0.f, f40}, b0{-1, 0.f, f40}, c0{-1, 0.f, f40};
    Slot a1{-1, 0.f, f40}, b1{-1, 0.f, f40}, c1{-1, 0.f, f40};
    Slot a2{-1, 0.f, f40}, b2{-1, 0.f, f40}, c2{-1, 0.f, f40};

    const float4* rows = (const float4*)gs;

    const float4* r0 = rows + (size_t)start * NC4;
    float4 v = (lane < NC4) ? r0[lane] : f40;
    float4 h = r0[0];

    for (long long i = start; i < end; ++i) {
        float4 vn = f40, hn = f40;
        if (i + 1 < end) {
            const float4* rn = rows + (size_t)(i + 1) * NC4;
            vn = (lane < NC4) ? rn[lane] : f40;
            hn = rn[0];
        }

        const float cnx = (h.x - lo0) * s0 - 1.0f;
        const float cny = (h.y - lo1) * s1 - 1.0f;
        const float cnz = (h.z - lo2) * s2 - 1.0f;
        int gx = (int)((cnx * 0.5f + 0.5f) * 127.0f);
        int gy = (int)((cny * 0.5f + 0.5f) * 127.0f);
        int gz = (int)((cnz * 0.5f + 0.5f) * 127.0f);
        gx = min(127, max(0, gx));
        gy = min(127, max(0, gy));
        gz = min(127, max(0, gz));
        const int cxy = __builtin_amdgcn_readfirstlane(gx * GRID_SZ + gy);
        const int cxz = __builtin_amdgcn_readfirstlane(gx * GRID_SZ + gz);
        const int cyz = __builtin_amdgcn_readfirstlane(gy * GRID_SZ + gz);

        const float alpha = 1.0f / (1.0f + __expf(-h.w));

        float4 vv = v;
        if (lane == 0) { vv.x = cnx; vv.y = cny; vv.z = cnz; }
        const float4 av = make_float4(vv.x * alpha, vv.y * alpha, vv.z * alpha, vv.w * alpha);

        plane_acc3(a0, b0, c0, cxy, alpha, av, nwr, dnr, pb0, db0, lane);
        plane_acc3(a1, b1, c1, cxz, alpha, av, nwr, dnr, pb1, db1, lane);
        plane_acc3(a2, b2, c2, cyz, alpha, av, nwr, dnr, pb2, db2, lane);

        v = vn; h = hn;
    }

    slot_flush_cm(a0, nwr, dnr, pb0, db0, lane);
    slot_flush_cm(b0, nwr, dnr, pb0, db0, lane);
    slot_flush_cm(c0, nwr, dnr, pb0, db0, lane);
    slot_flush_cm(a1, nwr, dnr, pb1, db1, lane);
    slot_flush_cm(b1, nwr, dnr, pb1, db1, lane);
    slot_flush_cm(c1, nwr, dnr, pb1, db1, lane);
    slot_flush_cm(a2, nwr, dnr, pb2, db2, lane);
    slot_flush_cm(b2, nwr, dnr, pb2, db2, lane);
    slot_flush_cm(c2, nwr, dnr, pb2, db2, lane);
}

#define TCELLS 64
__global__ __launch_bounds__(256) void xpose_kernel(const float* __restrict__ nw,
                                                    const float* __restrict__ dn,
                                                    float* __restrict__ out,
                                                    int K, size_t copyNw, size_t copyDn) {
    __shared__ float tile[TCELLS][197];   // pad 197: conflict-free column reads
    __shared__ float dinv[TCELLS];
    const int t = threadIdx.x;
    const int pg = blockIdx.x >> 8;              // plane index 0..B*3-1 (256 tiles/plane)
    const int c0 = (blockIdx.x & 255) * TCELLS;  // first cell of tile

    const float* src = nw + ((size_t)pg * G2 + c0) * NC;
    for (int i = t; i < TCELLS * NC4; i += 256) {
        const int cell = i / NC4;
        const int cp = i - cell * NC4;
        const float4* p = ((const float4*)(src + (size_t)cell * NC)) + cp;
        float4 v = *p;
        for (int r = 1; r < K; ++r) {
            float4 w = *(const float4*)((const float*)p + (size_t)r * copyNw);
            v.x += w.x; v.y += w.y; v.z += w.z; v.w += w.w;
        }
        float* dst = &tile[cell][cp * 4];
        dst[0] = v.x; dst[1] = v.y; dst[2] = v.z; dst[3] = v.w;
    }
    if (t < TCELLS) {
        float d = dn[pg * G2 + c0 + t];
        for (int r = 1; r < K; ++r) d += dn[(size_t)r * copyDn + pg * G2 + c0 + t];
        dinv[t] = 1.0f / fmaxf(d, 1e-6f);
    }
    __syncthreads();

    float* obase = out + (size_t)pg * NC * G2 + c0;
    for (int i = t; i < TCELLS * NC; i += 256) {
        const int c = i >> 6;
        const int cell = i & 63;
        obase[(size_t)c * G2 + cell] = tile[cell][c] * dinv[cell];
    }
}

// ---------- fallback (direct-to-out channel-major) path ----------

__device__ __forceinline__ void slot_flush(const Slot& s, float* __restrict__ out,
                                           float* __restrict__ den,
                                           size_t outPlaneBase, int denPlaneBase,
                                           int lane) {
    if (s.tag < 0) return;
    if (lane < NC4) {
        size_t base = outPlaneBase + (size_t)(4 * lane) * G2 + (size_t)s.tag;
        unsafeAtomicAdd(out + base,                 s.acc.x);
        unsafeAtomicAdd(out + base + (size_t)G2,    s.acc.y);
        unsafeAtomicAdd(out + base + (size_t)2*G2,  s.acc.z);
        unsafeAtomicAdd(out + base + (size_t)3*G2,  s.acc.w);
    }
    if (lane == 0) unsafeAtomicAdd(den + denPlaneBase + s.tag, s.den);
}

__device__ __forceinline__ void plane_acc(Slot& a, Slot& b, int cell, float alpha,
                                          const float4& av,
                                          float* __restrict__ out, float* __restrict__ den,
                                          size_t outPlaneBase, int denPlaneBase, int lane) {
    if (cell == a.tag) {
        a.acc.x += av.x; a.acc.y += av.y; a.acc.z += av.z; a.acc.w += av.w;
        a.den += alpha;
    } else if (cell == b.tag) {
        b.acc.x += av.x; b.acc.y += av.y; b.acc.z += av.z; b.acc.w += av.w;
        b.den += alpha;
    } else {
        if (b.den > a.den) { Slot t = a; a = b; b = t; }
        slot_flush(b, out, den, outPlaneBase, denPlaneBase, lane);
        b.tag = cell; b.den = alpha; b.acc = av;
    }
}

__global__ __launch_bounds__(256) void splat_kernel(
    const float* __restrict__ gs, const float* __restrict__ sb,
    float* __restrict__ out, float* __restrict__ den,
    int B, int N, int ppw) {
    const int lane = threadIdx.x & 63;
    const long long wave = (long long)blockIdx.x * (blockDim.x >> 6) + (threadIdx.x >> 6);
    const long long totalPts = (long long)B * N;
    long long start = wave * ppw;
    if (start >= totalPts) return;
    long long end = start + ppw;
    if (end > totalPts) end = totalPts;
    const int bb = (int)(start / N);

    const float lo0 = sb[0], hi0 = sb[1];
    const float lo1 = sb[2], hi1 = sb[3];
    const float lo2 = sb[4], hi2 = sb[5];
    const float s0 = 2.0f / (hi0 - lo0);
    const float s1 = 2.0f / (hi1 - lo1);
    const float s2 = 2.0f / (hi2 - lo2);

    const size_t ob0 = ((size_t)(bb * 3 + 0) * NC) * G2;
    const size_t ob1 = ((size_t)(bb * 3 + 1) * NC) * G2;
    const size_t ob2 = ((size_t)(bb * 3 + 2) * NC) * G2;
    const int db0 = (bb * 3 + 0) * G2;
    const int db1 = (bb * 3 + 1) * G2;
    const int db2 = (bb * 3 + 2) * G2;

    const float4 f40 = make_float4(0.f, 0.f, 0.f, 0.f);
    Slot a0{-1, 0.f, f40}, t0{-1, 0.f, f40};
    Slot a1{-1, 0.f, f40}, t1{-1, 0.f, f40};
    Slot a2{-1, 0.f, f40}, t2{-1, 0.f, f40};

    const float4* rows = (const float4*)gs;
    const float4* r0 = rows + (size_t)start * NC4;
    float4 v = (lane < NC4) ? r0[lane] : f40;
    float4 h = r0[0];

    for (long long i = start; i < end; ++i) {
        float4 vn = f40, hn = f40;
        if (i + 1 < end) {
            const float4* rn = rows + (size_t)(i + 1) * NC4;
            vn = (lane < NC4) ? rn[lane] : f40;
            hn = rn[0];
        }
        const float cnx = (h.x - lo0) * s0 - 1.0f;
        const float cny = (h.y - lo1) * s1 - 1.0f;
        const float cnz = (h.z - lo2) * s2 - 1.0f;
        int gx = (int)((cnx * 0.5f + 0.5f) * 127.0f);
        int gy = (int)((cny * 0.5f + 0.5f) * 127.0f);
        int gz = (int)((cnz * 0.5f + 0.5f) * 127.0f);
        gx = min(127, max(0, gx));
        gy = min(127, max(0, gy));
        gz = min(127, max(0, gz));
        const int cxy = __builtin_amdgcn_readfirstlane(gx * GRID_SZ + gy);
        const int cxz = __builtin_amdgcn_readfirstlane(gx * GRID_SZ + gz);
        const int cyz = __builtin_amdgcn_readfirstlane(gy * GRID_SZ + gz);

        const float alpha = 1.0f / (1.0f + __expf(-h.w));

        float4 vv = v;
        if (lane == 0) { vv.x = cnx; vv.y = cny; vv.z = cnz; }
        const float4 av = make_float4(vv.x * alpha, vv.y * alpha, vv.z * alpha, vv.w * alpha);

        plane_acc(a0, t0, cxy, alpha, av, out, den, ob0, db0, lane);
        plane_acc(a1, t1, cxz, alpha, av, out, den, ob1, db1, lane);
        plane_acc(a2, t2, cyz, alpha, av, out, den, ob2, db2, lane);

        v = vn; h = hn;
    }

    slot_flush(a0, out, den, ob0, db0, lane);
    slot_flush(t0, out, den, ob0, db0, lane);
    slot_flush(a1, out, den, ob1, db1, lane);
    slot_flush(t1, out, den, ob1, db1, lane);
    slot_flush(a2, out, den, ob2, db2, lane);
    slot_flush(t2, out, den, ob2, db2, lane);
}

__global__ void zero_kernel(float4* __restrict__ p, long long n4) {
    long long i = (long long)blockIdx.x * blockDim.x + threadIdx.x;
    long long stride = (long long)gridDim.x * blockDim.x;
    const float4 z = make_float4(0.f, 0.f, 0.f, 0.f);
    for (; i < n4; i += stride) p[i] = z;
}

__global__ void normalize_kernel(float* __restrict__ out, const float* __restrict__ den,
                                 int total4) {
    int idx = blockIdx.x * blockDim.x + threadIdx.x;
    const int stride = gridDim.x * blockDim.x;
    for (; idx < total4; idx += stride) {
        float4 v = ((float4*)out)[idx];
        const int e = idx * 4;
        const int cell = e & (G2 - 1);
        const int bp = e / (NC * G2);
        const float4 d = *(const float4*)(den + bp * G2 + cell);
        v.x /= fmaxf(d.x, 1e-6f);
        v.y /= fmaxf(d.y, 1e-6f);
        v.z /= fmaxf(d.z, 1e-6f);
        v.w /= fmaxf(d.w, 1e-6f);
        ((float4*)out)[idx] = v;
    }
}

extern "C" void kernel_launch(void* const* d_in, const int* in_sizes, int n_in,
                              void* d_out, int out_size, void* d_ws, size_t ws_size,
                              hipStream_t stream) {
    const float* gs = (const float*)d_in[0];
    const float* sb = (const float*)d_in[1];
    float* out = (float*)d_out;

    const int B = out_size / (3 * NC * G2);                            // 4
    const long long N = (long long)in_sizes[0] / ((long long)B * NC);  // 131072

    const size_t copyNw = (size_t)B * 3 * G2 * NC;      // floats per replica
    const size_t copyDn = (size_t)B * 3 * G2;
    const size_t copyBytes = (copyNw + copyDn) * sizeof(float);

    int K = (int)(ws_size / copyBytes);
    if (K > 4) K = 4;

    if (K >= 1) {
        const int PPW = 128;
        const long long waves = ((long long)B * N) / PPW;
        const int blocks = (int)((waves + 3) / 4);      // 1024

        float* nw = (float*)d_ws;
        float* dn = nw + (size_t)K * copyNw;
        const long long z4 = (long long)K * (long long)(copyNw + copyDn) / 4;
        zero_kernel<<<4096, 256, 0, stream>>>((float4*)d_ws, z4);
        splat_cm_kernel<<<blocks, 256, 0, stream>>>(gs, sb, nw, dn, B, (int)N, PPW,
                                                    K, copyNw, copyDn);
        const int xblocks = B * 3 * (G2 / TCELLS);      // 3072
        xpose_kernel<<<xblocks, 256, 0, stream>>>(nw, dn, out, K, copyNw, copyDn);
    } else {
        const int PPW = 64;
        const long long waves = ((long long)B * N) / PPW;
        const int blocks = (int)((waves + 3) / 4);
        float* den = (float*)d_ws;
        const long long out4 = (long long)out_size / 4;
        const long long den4 = (long long)copyDn / 4;
        zero_kernel<<<2048, 256, 0, stream>>>((float4*)out, out4);
        zero_kernel<<<256, 256, 0, stream>>>((float4*)den, den4);
        splat_kernel<<<blocks, 256, 0, stream>>>(gs, sb, out, den, B, (int)N, PPW);
        normalize_kernel<<<4096, 256, 0, stream>>>(out, den, (int)out4);
    }
}